// Round 4
// baseline (254.641 us; speedup 1.0000x reference)
//
#include <hip/hip_runtime.h>
#include <math.h>

// Problem constants
#define CH   64
#define FD   128
#define HS   64
#define FS   128
#define NB   8
#define NCTX 3

// workspace layout (float offsets) — only A-frags + bq used
#define WS_BQ   4227072                 // bq[64]
#define WS_AVH  4227136                 // conv A frags hi: [2][72][64][8] shorts
#define WS_AQH  4264000                 // qt A frags hi  : [2][8][64][8] shorts
#define WS_AQL  4268096
#define WS_AKH  4272192                 // key A frags
#define WS_AKL  4276288

typedef short  s16x8  __attribute__((ext_vector_type(8)));
typedef float  f32x16 __attribute__((ext_vector_type(16)));

__device__ inline unsigned short bf16_rne(float x) {
  unsigned u = __float_as_uint(x);
  u += 0x7FFFu + ((u >> 16) & 1u);
  return (unsigned short)(u >> 16);
}
__device__ inline void split2(float x, unsigned short& h, unsigned short& l) {
  h = bf16_rne(x);
  l = bf16_rne(x - __uint_as_float((unsigned)h << 16));
}

// ---------------------------------------------------------------------------
// afrag_prep: MFMA A-fragments (conv hi; qt/key hi+lo) + bq. 45 blocks.
// (unchanged)
// ---------------------------------------------------------------------------
__global__ __launch_bounds__(256) void afrag_prep(
    const float* __restrict__ Wc, const float* __restrict__ Wf,
    const float* __restrict__ bf, const float* __restrict__ Wk,
    const float* __restrict__ Vw, float* __restrict__ ws) {
  int id = blockIdx.x * 256 + threadIdx.x;
  unsigned short* avh = (unsigned short*)(ws + WS_AVH);
  unsigned short* aqh = (unsigned short*)(ws + WS_AQH);
  unsigned short* aql = (unsigned short*)(ws + WS_AQL);
  unsigned short* akh = (unsigned short*)(ws + WS_AKH);
  unsigned short* akl = (unsigned short*)(ws + WS_AKL);

  if (id < 9216) {                       // conv frags: hi only
    int tile = id / 4608, rem = id % 4608;
    int q = rem >> 6, l = rem & 63;
    int am = l & 31, kh = l >> 5;
    int c = tile * 32 + am, tap = q >> 3, kf = q & 7;
#pragma unroll
    for (int j = 0; j < 8; ++j) {
      int f = kf * 16 + kh * 8 + j;
      avh[id * 8 + j] = bf16_rne(Vw[(c * FD + f) * 9 + tap]);
    }
  } else if (id < 10240) {               // qt: Wq = Wc^T Wf inline
    int i2 = id - 9216;
    int tile = i2 >> 9, rem = i2 & 511;
    int q = rem >> 6, l = rem & 63;
    int am = l & 31, kh = l >> 5;
    int c = tile * 32 + am;
#pragma unroll
    for (int j = 0; j < 8; ++j) {
      int f = q * 16 + kh * 8 + j;
      float acc = 0.f;
      for (int d = 0; d < CH; ++d)
        acc = fmaf(Wc[d * CH + c], Wf[d * FD + f], acc);
      unsigned short h, lo; split2(acc, h, lo);
      aqh[i2 * 8 + j] = h; aql[i2 * 8 + j] = lo;
    }
  } else if (id < 11264) {               // keys: Wk direct
    int i3 = id - 10240;
    int tile = i3 >> 9, rem = i3 & 511;
    int q = rem >> 6, l = rem & 63;
    int am = l & 31, kh = l >> 5;
    int c = tile * 32 + am;
#pragma unroll
    for (int j = 0; j < 8; ++j) {
      int f = q * 16 + kh * 8 + j;
      unsigned short h, lo; split2(Wk[c * FD + f], h, lo);
      akh[i3 * 8 + j] = h; akl[i3 * 8 + j] = lo;
    }
  } else if (id < 11328) {               // bq = Wc^T bf
    int c = id - 11264;
    float acc = 0.f;
    for (int d = 0; d < CH; ++d) acc = fmaf(Wc[d * CH + c], bf[d], acc);
    ws[WS_BQ + c] = acc;
  }
}

// ---------------------------------------------------------------------------
// fused_kernel v4: block=(b,y), 512 thr, launch_bounds(512,4) -> 2 blocks/CU.
// Phase A = v1 exactly (3 barriers, results spill to LDS overlay).
// Phase B = BARRIER-FREE: wave w owns 32 contiguous px of row 2y+(w&1);
// lane = cl(16 c-groups of 4c) + 16*pp(4 px-quads). The 64-c logit reduce is
// 4 in-thread + 4-level shfl_xor butterfly within 16-lane groups — register
// only, no LDS, no barrier. 8 free-running waves/block x 2 blocks/CU keep
// ctx loads in flight continuously (TLP) instead of burst-stall lockstep.
// QT/VAL padded to [CH][65] so strided float2 reads are 2-way (free).
// ---------------------------------------------------------------------------
__global__ __launch_bounds__(512, 4) void fused_kernel(
    const float* __restrict__ m, const float* __restrict__ Vb,
    const float* __restrict__ bk, const float* __restrict__ ctx,
    float* __restrict__ out, const float* __restrict__ ws) {
  const int b = blockIdx.x >> 6, y = blockIdx.x & 63;
  const int t = threadIdx.x, lane = t & 63;
  const int wave = __builtin_amdgcn_readfirstlane(t >> 6);
  const int am = lane & 31, kh = lane >> 5;

  __shared__ __align__(16) union {
    short HI[3][8][66][2][8];            // 50688 B, phase A staging
    struct {                             // 33536 B, phase B (HI dead)
      float  QT[CH][65];                 // row y queries, with bq (+pad)
      float  VAL[CH][65];                // row y conv values, with Vb (+pad)
      float  L3[64];                     // row y self-logits
    } p;
  } U;
  __shared__ float l3red[2][64];

  // ---- zero x-borders (cols 0 and 65) ----
  if (t < 96) {
    int row = t / 32, kf = (t >> 2) & 7, khh = (t >> 1) & 1, col = (t & 1) * 65;
    s16x8 z;
#pragma unroll
    for (int j = 0; j < 8; ++j) z[j] = 0;
    *(s16x8*)&U.HI[row][kf][col][khh][0] = z;
  }

  // ---- stage hi: 48 wave-tasks (row,kf,kh), 6 per wave; coalesced reads ----
#pragma unroll
  for (int i = 0; i < 6; ++i) {
    const int tk = wave * 6 + i;               // 0..47
    const int row = tk >> 4, kf = (tk >> 1) & 7, khh = tk & 1;
    const int yy = y + row - 1;
    s16x8 hi;
    if (yy >= 0 && yy < HS) {
#pragma unroll
      for (int j = 0; j < 8; ++j) {
        const int f = kf * 16 + khh * 8 + j;
        hi[j] = (short)bf16_rne(m[((b * FD + f) * HS + yy) * HS + lane]);
      }
    } else {
#pragma unroll
      for (int j = 0; j < 8; ++j) hi[j] = 0;
    }
    *(s16x8*)&U.HI[row][kf][lane + 1][khh][0] = hi;
  }
  __syncthreads();                             // B1: HI staged

  const int ct = (wave >> 1) & 1;
  const int xh = wave & 1;
  const int x0 = xh * 32, ch0 = ct * 32;

  f32x16 acc, q1, q2, k1, k2;
  float l3part = 0.f;

  if (wave < 4) {
    // ---- conv: tile (ct,xh), all 72 K-chunks, A-hi x B-hi ----
    const unsigned short* avh = (const unsigned short*)(ws + WS_AVH);
#pragma unroll
    for (int i = 0; i < 16; ++i) acc[i] = 0.f;
#pragma unroll 8
    for (int q = 0; q < 72; ++q) {
      const int tap = q >> 3, kf = q & 7;
      const s16x8 ah = *(const s16x8*)(avh + ((ct * 72 + q) * 64 + lane) * 8);
      const s16x8 bh = *(const s16x8*)&U.HI[tap / 3][kf][x0 + am + tap % 3][kh][0];
      acc = __builtin_amdgcn_mfma_f32_32x32x16_bf16(ah, bh, acc, 0, 0, 0);
    }
  } else {
    // ---- qt + keys: K=128, 3-MFMA hi/lo split each ----
    const unsigned short* aqh = (const unsigned short*)(ws + WS_AQH);
    const unsigned short* aql = (const unsigned short*)(ws + WS_AQL);
    const unsigned short* akh = (const unsigned short*)(ws + WS_AKH);
    const unsigned short* akl = (const unsigned short*)(ws + WS_AKL);
#pragma unroll
    for (int i = 0; i < 16; ++i) { q1[i] = 0.f; q2[i] = 0.f; k1[i] = 0.f; k2[i] = 0.f; }
#pragma unroll
    for (int q = 0; q < 8; ++q) {
      const s16x8 bh = *(const s16x8*)&U.HI[1][q][x0 + am + 1][kh][0];
      s16x8 bl;
#pragma unroll
      for (int j = 0; j < 8; ++j) {
        const float mv = m[((b * FD + q * 16 + kh * 8 + j) * HS + y) * HS + x0 + am];
        const float hf = __uint_as_float(((unsigned)(unsigned short)bh[j]) << 16);
        bl[j] = (short)bf16_rne(mv - hf);
      }
      const s16x8 ah = *(const s16x8*)(aqh + ((ct * 8 + q) * 64 + lane) * 8);
      const s16x8 al = *(const s16x8*)(aql + ((ct * 8 + q) * 64 + lane) * 8);
      const s16x8 kah = *(const s16x8*)(akh + ((ct * 8 + q) * 64 + lane) * 8);
      const s16x8 kal = *(const s16x8*)(akl + ((ct * 8 + q) * 64 + lane) * 8);
      q1 = __builtin_amdgcn_mfma_f32_32x32x16_bf16(ah, bh, q1, 0, 0, 0);
      q1 = __builtin_amdgcn_mfma_f32_32x32x16_bf16(al, bh, q1, 0, 0, 0);
      q2 = __builtin_amdgcn_mfma_f32_32x32x16_bf16(ah, bl, q2, 0, 0, 0);
      k1 = __builtin_amdgcn_mfma_f32_32x32x16_bf16(kah, bh, k1, 0, 0, 0);
      k1 = __builtin_amdgcn_mfma_f32_32x32x16_bf16(kal, bh, k1, 0, 0, 0);
      k2 = __builtin_amdgcn_mfma_f32_32x32x16_bf16(kah, bl, k2, 0, 0, 0);
    }
  }
  __syncthreads();                             // B2: HI dead, overlay free

  // ---- spill accumulators to LDS overlay ----
  if (wave < 4) {
#pragma unroll
    for (int r = 0; r < 16; ++r) {
      const int c = ch0 + (r & 3) + 8 * (r >> 2) + 4 * kh;
      U.p.VAL[c][x0 + am] = acc[r] + Vb[c];
    }
  } else {
#pragma unroll
    for (int r = 0; r < 16; ++r) {
      const int c = ch0 + (r & 3) + 8 * (r >> 2) + 4 * kh;
      const float qvv = q1[r] + q2[r] + ws[WS_BQ + c];
      const float kvv = k1[r] + k2[r] + bk[c];
      U.p.QT[c][x0 + am] = qvv;
      l3part = fmaf(qvv, kvv, l3part);
    }
    if (ct == 1) l3red[xh][lane] = l3part;     // waves 6,7
  }
  __syncthreads();                             // B3: QT/VAL/l3red ready

  // ---- l3 finish: waves 4,5 ----
  if (wave == 4 || wave == 5) {
    float s = l3part + l3red[xh][lane];
    s += __shfl_xor(s, 32, 64);
    if (kh == 0) U.p.L3[x0 + am] = s;
  }
  __syncthreads();                             // B4: phase-B inputs ready

  // =======================================================================
  // Phase B: barrier-free. wave -> row u=wave&1, px quarter xq=wave>>1.
  // lane = cl(16) + 16*pp(4): c = 4*cl+i, px = xq*32 + j*16 + pp*4 + e.
  // =======================================================================
  const int cl = lane & 15;
  const int pp = lane >> 4;
  const int u  = wave & 1;
  const int xq = wave >> 1;
  const int hrow = 2 * y + u;
  const int cs = FS * FS;
  const float* cbase = ctx + (size_t)(b * NCTX * CH) * cs + (size_t)hrow * FS;
  float* obase = out + (size_t)(b * CH) * cs + (size_t)hrow * FS;

#pragma unroll 1
  for (int j = 0; j < 2; ++j) {
    const int px0 = xq * 32 + j * 16 + pp * 4;
    const int hx0 = px0 >> 1;

    float4 cv[3][4];
    float2 qv[4], vv[4];
#pragma unroll
    for (int i = 0; i < 4; ++i) {
      const int c = 4 * cl + i;
      qv[i] = *(const float2*)&U.p.QT[c][hx0];
      vv[i] = *(const float2*)&U.p.VAL[c][hx0];
#pragma unroll
      for (int n = 0; n < 3; ++n)
        cv[n][i] = *(const float4*)(cbase + (n * CH + c) * cs + px0);
    }

    // in-thread c-partials (4 c each)
    float4 pl[3];
#pragma unroll
    for (int n = 0; n < 3; ++n) {
      pl[n].x = pl[n].y = pl[n].z = pl[n].w = 0.f;
#pragma unroll
      for (int i = 0; i < 4; ++i) {
        pl[n].x = fmaf(cv[n][i].x, qv[i].x, pl[n].x);
        pl[n].y = fmaf(cv[n][i].y, qv[i].x, pl[n].y);
        pl[n].z = fmaf(cv[n][i].z, qv[i].y, pl[n].z);
        pl[n].w = fmaf(cv[n][i].w, qv[i].y, pl[n].w);
      }
    }
    // butterfly over the 16 c-groups (within 16-lane groups; register-only)
#pragma unroll
    for (int mk = 1; mk <= 8; mk <<= 1) {
#pragma unroll
      for (int n = 0; n < 3; ++n) {
        pl[n].x += __shfl_xor(pl[n].x, mk, 16);
        pl[n].y += __shfl_xor(pl[n].y, mk, 16);
        pl[n].z += __shfl_xor(pl[n].z, mk, 16);
        pl[n].w += __shfl_xor(pl[n].w, mk, 16);
      }
    }
    const float l3a = U.p.L3[hx0], l3b = U.p.L3[hx0 + 1];

    float A0[4], A1[4], A2[4], A3[4];
    const float* L0p = (const float*)&pl[0];
    const float* L1p = (const float*)&pl[1];
    const float* L2p = (const float*)&pl[2];
#pragma unroll
    for (int k = 0; k < 4; ++k) {
      float L0 = L0p[k], L1 = L1p[k], L2 = L2p[k];
      float L3v = (k < 2) ? l3a : l3b;
      float mx = fmaxf(fmaxf(L0, L1), fmaxf(L2, L3v));
      float e0 = __expf(L0 - mx), e1 = __expf(L1 - mx);
      float e2 = __expf(L2 - mx), e3 = __expf(L3v - mx);
      float inv = 1.f / (e0 + e1 + e2 + e3);
      A0[k] = e0 * inv; A1[k] = e1 * inv; A2[k] = e2 * inv; A3[k] = e3 * inv;
    }

#pragma unroll
    for (int i = 0; i < 4; ++i) {
      const int c = 4 * cl + i;
      float4 o;
      o.x = fmaf(A0[0], cv[0][i].x, fmaf(A1[0], cv[1][i].x, fmaf(A2[0], cv[2][i].x, A3[0] * vv[i].x)));
      o.y = fmaf(A0[1], cv[0][i].y, fmaf(A1[1], cv[1][i].y, fmaf(A2[1], cv[2][i].y, A3[1] * vv[i].x)));
      o.z = fmaf(A0[2], cv[0][i].z, fmaf(A1[2], cv[1][i].z, fmaf(A2[2], cv[2][i].z, A3[2] * vv[i].y)));
      o.w = fmaf(A0[3], cv[0][i].w, fmaf(A1[3], cv[1][i].w, fmaf(A2[3], cv[2][i].w, A3[3] * vv[i].y)));
      *(float4*)(obase + c * cs + px0) = o;
    }
  }
}

// ---------------------------------------------------------------------------
extern "C" void kernel_launch(void* const* d_in, const int* in_sizes, int n_in,
                              void* d_out, int out_size, void* d_ws, size_t ws_size,
                              hipStream_t stream) {
  const float* ctx = (const float*)d_in[0];
  const float* ms  = (const float*)d_in[1];
  const float* Wc  = (const float*)d_in[2];
  // d_in[3] = bc : cancels in softmax
  const float* Wf  = (const float*)d_in[4];
  const float* bf  = (const float*)d_in[5];
  const float* Wk  = (const float*)d_in[6];
  const float* bk  = (const float*)d_in[7];
  const float* Vw  = (const float*)d_in[8];
  const float* Vb  = (const float*)d_in[9];
  float* ws  = (float*)d_ws;
  float* out = (float*)d_out;

  afrag_prep<<<45, 256, 0, stream>>>(Wc, Wf, bf, Wk, Vw, ws);
  fused_kernel<<<NB * HS, 512, 0, stream>>>(ms, Vb, bk, ctx, out, ws);
}

// Round 5
// 248.962 us; speedup vs baseline: 1.0228x; 1.0228x over previous
//
#include <hip/hip_runtime.h>
#include <math.h>

// Problem constants
#define CH   64
#define FD   128
#define HS   64
#define FS   128
#define NB   8
#define NCTX 3

// workspace layout (float offsets) — only A-frags + bq used
#define WS_BQ   4227072                 // bq[64]
#define WS_AVH  4227136                 // conv A frags hi: [2][72][64][8] shorts
#define WS_AQH  4264000                 // qt A frags hi  : [2][8][64][8] shorts
#define WS_AQL  4268096
#define WS_AKH  4272192                 // key A frags
#define WS_AKL  4276288

typedef short  s16x8  __attribute__((ext_vector_type(8)));
typedef float  f32x16 __attribute__((ext_vector_type(16)));

__device__ inline unsigned short bf16_rne(float x) {
  unsigned u = __float_as_uint(x);
  u += 0x7FFFu + ((u >> 16) & 1u);
  return (unsigned short)(u >> 16);
}
__device__ inline void split2(float x, unsigned short& h, unsigned short& l) {
  h = bf16_rne(x);
  l = bf16_rne(x - __uint_as_float((unsigned)h << 16));
}

// ---------------------------------------------------------------------------
// afrag_prep: MFMA A-fragments (conv hi; qt/key hi+lo) + bq. 45 blocks.
// (unchanged)
// ---------------------------------------------------------------------------
__global__ __launch_bounds__(256) void afrag_prep(
    const float* __restrict__ Wc, const float* __restrict__ Wf,
    const float* __restrict__ bf, const float* __restrict__ Wk,
    const float* __restrict__ Vw, float* __restrict__ ws) {
  int id = blockIdx.x * 256 + threadIdx.x;
  unsigned short* avh = (unsigned short*)(ws + WS_AVH);
  unsigned short* aqh = (unsigned short*)(ws + WS_AQH);
  unsigned short* aql = (unsigned short*)(ws + WS_AQL);
  unsigned short* akh = (unsigned short*)(ws + WS_AKH);
  unsigned short* akl = (unsigned short*)(ws + WS_AKL);

  if (id < 9216) {                       // conv frags: hi only
    int tile = id / 4608, rem = id % 4608;
    int q = rem >> 6, l = rem & 63;
    int am = l & 31, kh = l >> 5;
    int c = tile * 32 + am, tap = q >> 3, kf = q & 7;
#pragma unroll
    for (int j = 0; j < 8; ++j) {
      int f = kf * 16 + kh * 8 + j;
      avh[id * 8 + j] = bf16_rne(Vw[(c * FD + f) * 9 + tap]);
    }
  } else if (id < 10240) {               // qt: Wq = Wc^T Wf inline
    int i2 = id - 9216;
    int tile = i2 >> 9, rem = i2 & 511;
    int q = rem >> 6, l = rem & 63;
    int am = l & 31, kh = l >> 5;
    int c = tile * 32 + am;
#pragma unroll
    for (int j = 0; j < 8; ++j) {
      int f = q * 16 + kh * 8 + j;
      float acc = 0.f;
      for (int d = 0; d < CH; ++d)
        acc = fmaf(Wc[d * CH + c], Wf[d * FD + f], acc);
      unsigned short h, lo; split2(acc, h, lo);
      aqh[i2 * 8 + j] = h; aql[i2 * 8 + j] = lo;
    }
  } else if (id < 11264) {               // keys: Wk direct
    int i3 = id - 10240;
    int tile = i3 >> 9, rem = i3 & 511;
    int q = rem >> 6, l = rem & 63;
    int am = l & 31, kh = l >> 5;
    int c = tile * 32 + am;
#pragma unroll
    for (int j = 0; j < 8; ++j) {
      int f = q * 16 + kh * 8 + j;
      unsigned short h, lo; split2(Wk[c * FD + f], h, lo);
      akh[i3 * 8 + j] = h; akl[i3 * 8 + j] = lo;
    }
  } else if (id < 11328) {               // bq = Wc^T bf
    int c = id - 11264;
    float acc = 0.f;
    for (int d = 0; d < CH; ++d) acc = fmaf(Wc[d * CH + c], bf[d], acc);
    ws[WS_BQ + c] = acc;
  }
}

// ---------------------------------------------------------------------------
// fused_kernel v5 = round-1 structure (best: 72.4us) + phase-A latency fixes:
//  (1) BL lo-tile staged to LDS during staging (qt loop loses its 64 global
//      m re-reads per wave);
//  (2) conv loop: 9 groups of 8, next group's 8 A-frags register-prefetched
//      under current group's 8 MFMA (72 serialized L2 windows -> ~9);
//  (3) qt loop: 1-deep register prefetch of the 4 qt/key frags;
//  (4) launch_bounds(512,4): VGPR cap 128 so prefetch batches stay in flight
//      (round-1's VGPR=60 serialized every load batch).
// Phase B is round-1 verbatim. LDS 66.5KB -> 2 blocks/CU.
// ---------------------------------------------------------------------------
__global__ __launch_bounds__(512, 4) void fused_kernel(
    const float* __restrict__ m, const float* __restrict__ Vb,
    const float* __restrict__ bk, const float* __restrict__ ctx,
    float* __restrict__ out, const float* __restrict__ ws) {
  const int b = blockIdx.x >> 6, y = blockIdx.x & 63;
  const int t = threadIdx.x, lane = t & 63;
  const int wave = __builtin_amdgcn_readfirstlane(t >> 6);
  const int am = lane & 31, kh = lane >> 5;

  __shared__ __align__(16) union {
    short HI[3][8][66][2][8];            // 50688 B, phase A staging
    struct {                             // 39168 B, phase B (HI dead)
      float  QT[CH * HS];                // row y queries, with bq
      float  VAL[CH * HS];               // row y conv values, with Vb
      float4 wpart[2][4][3][16];         // [u][wave-in-unit][n][quad]
      float  L3row[HS];                  // row y self-logits
    } p;
  } U;
  __shared__ __align__(16) short BL[8][66][2][8];  // 16896 B: row-1 lo tile
  __shared__ float l3red[2][64];

  // ---- zero x-borders (cols 0 and 65) ----
  if (t < 96) {
    int row = t / 32, kf = (t >> 2) & 7, khh = (t >> 1) & 1, col = (t & 1) * 65;
    s16x8 z;
#pragma unroll
    for (int j = 0; j < 8; ++j) z[j] = 0;
    *(s16x8*)&U.HI[row][kf][col][khh][0] = z;
  }

  // ---- stage hi (+ lo for row 1): 48 wave-tasks (row,kf,kh), 6 per wave ----
#pragma unroll
  for (int i = 0; i < 6; ++i) {
    const int tk = wave * 6 + i;               // 0..47
    const int row = tk >> 4, kf = (tk >> 1) & 7, khh = tk & 1;
    const int yy = y + row - 1;
    s16x8 hi;
    if (yy >= 0 && yy < HS) {
      float mv[8];
#pragma unroll
      for (int j = 0; j < 8; ++j) {
        const int f = kf * 16 + khh * 8 + j;
        mv[j] = m[((b * FD + f) * HS + yy) * HS + lane];
      }
#pragma unroll
      for (int j = 0; j < 8; ++j) hi[j] = (short)bf16_rne(mv[j]);
      if (row == 1) {                          // lo residual for qt/keys
        s16x8 lo;
#pragma unroll
        for (int j = 0; j < 8; ++j) {
          const float hf = __uint_as_float(((unsigned)(unsigned short)hi[j]) << 16);
          lo[j] = (short)bf16_rne(mv[j] - hf);
        }
        *(s16x8*)&BL[kf][lane + 1][khh][0] = lo;
      }
    } else {
#pragma unroll
      for (int j = 0; j < 8; ++j) hi[j] = 0;
    }
    *(s16x8*)&U.HI[row][kf][lane + 1][khh][0] = hi;
  }
  __syncthreads();                             // B1: HI + BL staged

  const int ct = (wave >> 1) & 1;
  const int xh = wave & 1;
  const int x0 = xh * 32, ch0 = ct * 32;

  f32x16 acc, q1, q2, k1, k2;
  float l3part = 0.f;

  if (wave < 4) {
    // ---- conv: 72 K-chunks as 9 groups of 8; next group reg-prefetched ----
    const unsigned short* avh = (const unsigned short*)(ws + WS_AVH);
#pragma unroll
    for (int i = 0; i < 16; ++i) acc[i] = 0.f;
    s16x8 A[8];
#pragma unroll
    for (int i = 0; i < 8; ++i)
      A[i] = *(const s16x8*)(avh + ((ct * 72 + i) * 64 + lane) * 8);
#pragma unroll 1
    for (int g = 0; g < 9; ++g) {
      s16x8 Bv[8];
      const int qb = (g < 8) ? (g * 8 + 8) : 0;  // prefetch base (wraps, unused)
#pragma unroll
      for (int i = 0; i < 8; ++i)
        Bv[i] = *(const s16x8*)(avh + ((ct * 72 + qb + i) * 64 + lane) * 8);
      const int tap = g, tr = tap / 3, tc = tap % 3;
#pragma unroll
      for (int i = 0; i < 8; ++i) {
        const s16x8 bh = *(const s16x8*)&U.HI[tr][i][x0 + am + tc][kh][0];
        acc = __builtin_amdgcn_mfma_f32_32x32x16_bf16(A[i], bh, acc, 0, 0, 0);
      }
#pragma unroll
      for (int i = 0; i < 8; ++i) A[i] = Bv[i];
    }
  } else {
    // ---- qt + keys: K=128, hi/lo split; frags 1-deep prefetched; bl from LDS ----
    const unsigned short* aqh = (const unsigned short*)(ws + WS_AQH);
    const unsigned short* aql = (const unsigned short*)(ws + WS_AQL);
    const unsigned short* akh = (const unsigned short*)(ws + WS_AKH);
    const unsigned short* akl = (const unsigned short*)(ws + WS_AKL);
#pragma unroll
    for (int i = 0; i < 16; ++i) { q1[i] = 0.f; q2[i] = 0.f; k1[i] = 0.f; k2[i] = 0.f; }
    s16x8 ah  = *(const s16x8*)(aqh + ((ct * 8 + 0) * 64 + lane) * 8);
    s16x8 al  = *(const s16x8*)(aql + ((ct * 8 + 0) * 64 + lane) * 8);
    s16x8 kah = *(const s16x8*)(akh + ((ct * 8 + 0) * 64 + lane) * 8);
    s16x8 kal = *(const s16x8*)(akl + ((ct * 8 + 0) * 64 + lane) * 8);
#pragma unroll 1
    for (int q = 0; q < 8; ++q) {
      const int qn = (q < 7) ? (q + 1) : 0;    // prefetch next (wraps, unused)
      s16x8 ahn  = *(const s16x8*)(aqh + ((ct * 8 + qn) * 64 + lane) * 8);
      s16x8 aln  = *(const s16x8*)(aql + ((ct * 8 + qn) * 64 + lane) * 8);
      s16x8 kahn = *(const s16x8*)(akh + ((ct * 8 + qn) * 64 + lane) * 8);
      s16x8 kaln = *(const s16x8*)(akl + ((ct * 8 + qn) * 64 + lane) * 8);
      const s16x8 bh = *(const s16x8*)&U.HI[1][q][x0 + am + 1][kh][0];
      const s16x8 bl = *(const s16x8*)&BL[q][x0 + am + 1][kh][0];
      q1 = __builtin_amdgcn_mfma_f32_32x32x16_bf16(ah,  bh, q1, 0, 0, 0);
      q1 = __builtin_amdgcn_mfma_f32_32x32x16_bf16(al,  bh, q1, 0, 0, 0);
      q2 = __builtin_amdgcn_mfma_f32_32x32x16_bf16(ah,  bl, q2, 0, 0, 0);
      k1 = __builtin_amdgcn_mfma_f32_32x32x16_bf16(kah, bh, k1, 0, 0, 0);
      k1 = __builtin_amdgcn_mfma_f32_32x32x16_bf16(kal, bh, k1, 0, 0, 0);
      k2 = __builtin_amdgcn_mfma_f32_32x32x16_bf16(kah, bl, k2, 0, 0, 0);
      ah = ahn; al = aln; kah = kahn; kal = kaln;
    }
  }
  __syncthreads();                             // B2: HI/BL dead, overlay free

  // ---- spill accumulators to LDS overlay ----
  if (wave < 4) {
#pragma unroll
    for (int r = 0; r < 16; ++r) {
      const int c = ch0 + (r & 3) + 8 * (r >> 2) + 4 * kh;
      U.p.VAL[c * HS + x0 + am] = acc[r] + Vb[c];
    }
  } else {
#pragma unroll
    for (int r = 0; r < 16; ++r) {
      const int c = ch0 + (r & 3) + 8 * (r >> 2) + 4 * kh;
      const float qvv = q1[r] + q2[r] + ws[WS_BQ + c];
      const float kvv = k1[r] + k2[r] + bk[c];
      U.p.QT[c * HS + x0 + am] = qvv;
      l3part = fmaf(qvv, kvv, l3part);
    }
    if (ct == 1) l3red[xh][lane] = l3part;     // waves 6,7
  }
  __syncthreads();                             // B3: QT/VAL/l3red ready

  // ---- l3 finish: waves 4,5 ----
  if (wave == 4 || wave == 5) {
    float s = l3part + l3red[xh][lane];
    s += __shfl_xor(s, 32, 64);
    if (kh == 0) U.p.L3row[x0 + am] = s;
  }
  __syncthreads();                             // B4: phase-B inputs ready

  // =======================================================================
  // Phase B: round-1 verbatim. rows 2y (u=0), 2y+1 (u=1); x halves looped.
  // =======================================================================
  const int u    = t >> 8;                     // output row sub-block
  const int tt   = t & 255;
  const int quad = tt & 15;
  const int cg   = tt >> 4;
  const int wv   = tt >> 6;                    // wave within unit (0..3)
  const int c0   = cg * 4;
  const int hrow = 2 * y + u;
  const int cs = FS * FS, ns = CH * FS * FS;

  float* op = out + (size_t)(b * CH) * FS * FS + (size_t)hrow * FS;
  const float* cb = ctx + (size_t)(b * NCTX * CH) * cs + (size_t)hrow * FS;

#pragma unroll 1
  for (int x2 = 0; x2 < 2; ++x2) {
    const int x = x2 * 64 + quad * 4;
    const int w2 = x >> 1;

    float4 cv[3][4];
    float2 qv[4];
#pragma unroll
    for (int j = 0; j < 4; ++j) {
      const int c = c0 + j;
      cv[0][j] = *(const float4*)(cb + x + c * cs);
      cv[1][j] = *(const float4*)(cb + x + ns + c * cs);
      cv[2][j] = *(const float4*)(cb + x + 2 * ns + c * cs);
      qv[j] = *(const float2*)&U.p.QT[c * HS + w2];
    }

    float4 pl[3];
#pragma unroll
    for (int n = 0; n < 3; ++n) {
      pl[n].x = pl[n].y = pl[n].z = pl[n].w = 0.f;
#pragma unroll
      for (int j = 0; j < 4; ++j) {
        pl[n].x = fmaf(cv[n][j].x, qv[j].x, pl[n].x);
        pl[n].y = fmaf(cv[n][j].y, qv[j].x, pl[n].y);
        pl[n].z = fmaf(cv[n][j].z, qv[j].y, pl[n].z);
        pl[n].w = fmaf(cv[n][j].w, qv[j].y, pl[n].w);
      }
    }

    // in-wave reduce over the wave's 4 c-groups (lanes ^16, ^32)
#pragma unroll
    for (int n = 0; n < 3; ++n) {
      pl[n].x += __shfl_xor(pl[n].x, 16, 64);
      pl[n].y += __shfl_xor(pl[n].y, 16, 64);
      pl[n].z += __shfl_xor(pl[n].z, 16, 64);
      pl[n].w += __shfl_xor(pl[n].w, 16, 64);
      pl[n].x += __shfl_xor(pl[n].x, 32, 64);
      pl[n].y += __shfl_xor(pl[n].y, 32, 64);
      pl[n].z += __shfl_xor(pl[n].z, 32, 64);
      pl[n].w += __shfl_xor(pl[n].w, 32, 64);
    }
    __syncthreads();                           // wpart free (prev iter read)
    if ((lane >> 4) == 0) {
#pragma unroll
      for (int n = 0; n < 3; ++n) U.p.wpart[u][wv][n][quad] = pl[n];
    }
    __syncthreads();                           // wpart ready

    float4 L[3];
#pragma unroll
    for (int n = 0; n < 3; ++n) {
      const float4 p0 = U.p.wpart[u][0][n][quad];
      const float4 p1 = U.p.wpart[u][1][n][quad];
      const float4 p2 = U.p.wpart[u][2][n][quad];
      const float4 p3 = U.p.wpart[u][3][n][quad];
      L[n].x = (p0.x + p1.x) + (p2.x + p3.x);
      L[n].y = (p0.y + p1.y) + (p2.y + p3.y);
      L[n].z = (p0.z + p1.z) + (p2.z + p3.z);
      L[n].w = (p0.w + p1.w) + (p2.w + p3.w);
    }
    const float2 l3v = *(const float2*)&U.p.L3row[w2];

    float A0[4], A1[4], A2[4], A3[4];
    const float* L0p = (const float*)&L[0];
    const float* L1p = (const float*)&L[1];
    const float* L2p = (const float*)&L[2];
#pragma unroll
    for (int k = 0; k < 4; ++k) {
      float L0 = L0p[k], L1 = L1p[k], L2 = L2p[k];
      float L3 = (k < 2) ? l3v.x : l3v.y;
      float mx = fmaxf(fmaxf(L0, L1), fmaxf(L2, L3));
      float e0 = __expf(L0 - mx), e1 = __expf(L1 - mx);
      float e2 = __expf(L2 - mx), e3 = __expf(L3 - mx);
      float inv = 1.f / (e0 + e1 + e2 + e3);
      A0[k] = e0 * inv; A1[k] = e1 * inv; A2[k] = e2 * inv; A3[k] = e3 * inv;
    }

#pragma unroll
    for (int j = 0; j < 4; ++j) {
      const int c = c0 + j;
      const float2 vv = *(const float2*)&U.p.VAL[c * HS + w2];
      float4 o;
      o.x = fmaf(A0[0], cv[0][j].x, fmaf(A1[0], cv[1][j].x, fmaf(A2[0], cv[2][j].x, A3[0] * vv.x)));
      o.y = fmaf(A0[1], cv[0][j].y, fmaf(A1[1], cv[1][j].y, fmaf(A2[1], cv[2][j].y, A3[1] * vv.x)));
      o.z = fmaf(A0[2], cv[0][j].z, fmaf(A1[2], cv[1][j].z, fmaf(A2[2], cv[2][j].z, A3[2] * vv.y)));
      o.w = fmaf(A0[3], cv[0][j].w, fmaf(A1[3], cv[1][j].w, fmaf(A2[3], cv[2][j].w, A3[3] * vv.y)));
      *(float4*)(op + x + c * cs) = o;
    }
  }
}

// ---------------------------------------------------------------------------
extern "C" void kernel_launch(void* const* d_in, const int* in_sizes, int n_in,
                              void* d_out, int out_size, void* d_ws, size_t ws_size,
                              hipStream_t stream) {
  const float* ctx = (const float*)d_in[0];
  const float* ms  = (const float*)d_in[1];
  const float* Wc  = (const float*)d_in[2];
  // d_in[3] = bc : cancels in softmax
  const float* Wf  = (const float*)d_in[4];
  const float* bf  = (const float*)d_in[5];
  const float* Wk  = (const float*)d_in[6];
  const float* bk  = (const float*)d_in[7];
  const float* Vw  = (const float*)d_in[8];
  const float* Vb  = (const float*)d_in[9];
  float* ws  = (float*)d_ws;
  float* out = (float*)d_out;

  afrag_prep<<<45, 256, 0, stream>>>(Wc, Wf, bf, Wk, Vw, ws);
  fused_kernel<<<NB * HS, 512, 0, stream>>>(ms, Vb, bk, ctx, out, ws);
}

// Round 6
// 244.473 us; speedup vs baseline: 1.0416x; 1.0184x over previous
//
#include <hip/hip_runtime.h>
#include <math.h>

// Problem constants
#define CH   64
#define FD   128
#define HS   64
#define FS   128
#define NB   8
#define NCTX 3

// workspace layout (float offsets) — only A-frags + bq used
#define WS_BQ   4227072                 // bq[64]
#define WS_AVH  4227136                 // conv A frags hi: [2][72][64][8] shorts
#define WS_AQH  4264000                 // qt A frags hi  : [2][8][64][8] shorts
#define WS_AQL  4268096
#define WS_AKH  4272192                 // key A frags
#define WS_AKL  4276288

typedef short  s16x8  __attribute__((ext_vector_type(8)));
typedef float  f32x16 __attribute__((ext_vector_type(16)));

__device__ inline unsigned short bf16_rne(float x) {
  unsigned u = __float_as_uint(x);
  u += 0x7FFFu + ((u >> 16) & 1u);
  return (unsigned short)(u >> 16);
}
__device__ inline void split2(float x, unsigned short& h, unsigned short& l) {
  h = bf16_rne(x);
  l = bf16_rne(x - __uint_as_float((unsigned)h << 16));
}

// ---------------------------------------------------------------------------
// afrag_prep: MFMA A-fragments (conv hi; qt/key hi+lo) + bq. 45 blocks.
// (unchanged)
// ---------------------------------------------------------------------------
__global__ __launch_bounds__(256) void afrag_prep(
    const float* __restrict__ Wc, const float* __restrict__ Wf,
    const float* __restrict__ bf, const float* __restrict__ Wk,
    const float* __restrict__ Vw, float* __restrict__ ws) {
  int id = blockIdx.x * 256 + threadIdx.x;
  unsigned short* avh = (unsigned short*)(ws + WS_AVH);
  unsigned short* aqh = (unsigned short*)(ws + WS_AQH);
  unsigned short* aql = (unsigned short*)(ws + WS_AQL);
  unsigned short* akh = (unsigned short*)(ws + WS_AKH);
  unsigned short* akl = (unsigned short*)(ws + WS_AKL);

  if (id < 9216) {                       // conv frags: hi only
    int tile = id / 4608, rem = id % 4608;
    int q = rem >> 6, l = rem & 63;
    int am = l & 31, kh = l >> 5;
    int c = tile * 32 + am, tap = q >> 3, kf = q & 7;
#pragma unroll
    for (int j = 0; j < 8; ++j) {
      int f = kf * 16 + kh * 8 + j;
      avh[id * 8 + j] = bf16_rne(Vw[(c * FD + f) * 9 + tap]);
    }
  } else if (id < 10240) {               // qt: Wq = Wc^T Wf inline
    int i2 = id - 9216;
    int tile = i2 >> 9, rem = i2 & 511;
    int q = rem >> 6, l = rem & 63;
    int am = l & 31, kh = l >> 5;
    int c = tile * 32 + am;
#pragma unroll
    for (int j = 0; j < 8; ++j) {
      int f = q * 16 + kh * 8 + j;
      float acc = 0.f;
      for (int d = 0; d < CH; ++d)
        acc = fmaf(Wc[d * CH + c], Wf[d * FD + f], acc);
      unsigned short h, lo; split2(acc, h, lo);
      aqh[i2 * 8 + j] = h; aql[i2 * 8 + j] = lo;
    }
  } else if (id < 11264) {               // keys: Wk direct
    int i3 = id - 10240;
    int tile = i3 >> 9, rem = i3 & 511;
    int q = rem >> 6, l = rem & 63;
    int am = l & 31, kh = l >> 5;
    int c = tile * 32 + am;
#pragma unroll
    for (int j = 0; j < 8; ++j) {
      int f = q * 16 + kh * 8 + j;
      unsigned short h, lo; split2(Wk[c * FD + f], h, lo);
      akh[i3 * 8 + j] = h; akl[i3 * 8 + j] = lo;
    }
  } else if (id < 11328) {               // bq = Wc^T bf
    int c = id - 11264;
    float acc = 0.f;
    for (int d = 0; d < CH; ++d) acc = fmaf(Wc[d * CH + c], bf[d], acc);
    ws[WS_BQ + c] = acc;
  }
}

// ---------------------------------------------------------------------------
// fused_kernel v6:
//  Phase A: v5 + ENFORCED frag-load pipelining — ping-pong reg buffers
//    (Abuf[2][8], F[2][4]) with sched_barrier(0) fences so hipcc cannot sink
//    the prefetch loads back to their use (v5's VGPR=64 proved it folded the
//    pipeline). 72 serialized L2 windows -> ~9 (conv), 32 -> ~8 (qt).
//  Phase B: BARRIER-FREE streaming. lane = pl(8 px-quads)+cq(8 c-groups),
//    8 c in-thread; the 64-c logit reduce = in-thread + shfl_xor 8/16/32
//    (in-wave). Each wave owns 32px x full-c of one output row; 8 waves =
//    2 rows x 128 px in ONE pass, zero barriers/LDS after the handoff.
//    ctx re-read for the output pass comes from hot L2 (keeps VGPR <= 128).
//  QT/VAL at stride 66 (even -> float2-aligned, ~2-way banks = free).
// ---------------------------------------------------------------------------
__global__ __launch_bounds__(512, 4) void fused_kernel(
    const float* __restrict__ m, const float* __restrict__ Vb,
    const float* __restrict__ bk, const float* __restrict__ ctx,
    float* __restrict__ out, const float* __restrict__ ws) {
  const int b = blockIdx.x >> 6, y = blockIdx.x & 63;
  const int t = threadIdx.x, lane = t & 63;
  const int wave = __builtin_amdgcn_readfirstlane(t >> 6);
  const int am = lane & 31, kh = lane >> 5;

  __shared__ __align__(16) union {
    short HI[3][8][66][2][8];            // 50688 B, phase A staging
    struct {                             // 34048 B, phase B (HI dead)
      float QT[CH * 66];                 // row y queries, with bq (stride 66)
      float VAL[CH * 66];                // row y conv values, with Vb
      float L3[64];                      // row y self-logits
    } p;
  } U;
  __shared__ __align__(16) short BL[8][66][2][8];  // 16896 B: row-1 lo tile
  __shared__ float l3red[2][64];

  // ---- zero x-borders (cols 0 and 65) ----
  if (t < 96) {
    int row = t / 32, kf = (t >> 2) & 7, khh = (t >> 1) & 1, col = (t & 1) * 65;
    s16x8 z;
#pragma unroll
    for (int j = 0; j < 8; ++j) z[j] = 0;
    *(s16x8*)&U.HI[row][kf][col][khh][0] = z;
  }

  // ---- stage hi (+ lo for row 1): 48 wave-tasks (row,kf,kh), 6 per wave ----
#pragma unroll
  for (int i = 0; i < 6; ++i) {
    const int tk = wave * 6 + i;               // 0..47
    const int row = tk >> 4, kf = (tk >> 1) & 7, khh = tk & 1;
    const int yy = y + row - 1;
    s16x8 hi;
    if (yy >= 0 && yy < HS) {
      float mv[8];
#pragma unroll
      for (int j = 0; j < 8; ++j) {
        const int f = kf * 16 + khh * 8 + j;
        mv[j] = m[((b * FD + f) * HS + yy) * HS + lane];
      }
#pragma unroll
      for (int j = 0; j < 8; ++j) hi[j] = (short)bf16_rne(mv[j]);
      if (row == 1) {                          // lo residual for qt/keys
        s16x8 lo;
#pragma unroll
        for (int j = 0; j < 8; ++j) {
          const float hf = __uint_as_float(((unsigned)(unsigned short)hi[j]) << 16);
          lo[j] = (short)bf16_rne(mv[j] - hf);
        }
        *(s16x8*)&BL[kf][lane + 1][khh][0] = lo;
      }
    } else {
#pragma unroll
      for (int j = 0; j < 8; ++j) hi[j] = 0;
    }
    *(s16x8*)&U.HI[row][kf][lane + 1][khh][0] = hi;
  }
  __syncthreads();                             // B1: HI + BL staged

  const int ct = (wave >> 1) & 1;
  const int xh = wave & 1;
  const int x0 = xh * 32, ch0 = ct * 32;

  f32x16 acc, q1, q2, k1, k2;
  float l3part = 0.f;

  if (wave < 4) {
    // ---- conv: 9 taps x 8 kf; ping-pong 8-frag prefetch, fence-enforced ----
    const unsigned short* base =
        (const unsigned short*)(ws + WS_AVH) + ((size_t)ct * 72 * 64 + lane) * 8;
#pragma unroll
    for (int i = 0; i < 16; ++i) acc[i] = 0.f;
    s16x8 Abuf[2][8];
#pragma unroll
    for (int i = 0; i < 8; ++i)
      Abuf[0][i] = *(const s16x8*)(base + i * 512);
#pragma unroll
    for (int g = 0; g < 9; ++g) {
      if (g < 8) {
#pragma unroll
        for (int i = 0; i < 8; ++i)
          Abuf[(g + 1) & 1][i] = *(const s16x8*)(base + ((g + 1) * 8 + i) * 512);
      }
      __builtin_amdgcn_sched_barrier(0);       // loads stay issued HERE
      const int tr = g / 3, tc = g % 3;
#pragma unroll
      for (int i = 0; i < 8; ++i) {
        const s16x8 bh = *(const s16x8*)&U.HI[tr][i][x0 + am + tc][kh][0];
        acc = __builtin_amdgcn_mfma_f32_32x32x16_bf16(Abuf[g & 1][i], bh, acc, 0, 0, 0);
      }
      __builtin_amdgcn_sched_barrier(0);
    }
  } else {
    // ---- qt + keys: ping-pong 4-frag prefetch, fence-enforced ----
    const unsigned short* bq0 =
        (const unsigned short*)(ws + WS_AQH) + ((size_t)ct * 8 * 64 + lane) * 8;
    const unsigned short* bq1 =
        (const unsigned short*)(ws + WS_AQL) + ((size_t)ct * 8 * 64 + lane) * 8;
    const unsigned short* bk0 =
        (const unsigned short*)(ws + WS_AKH) + ((size_t)ct * 8 * 64 + lane) * 8;
    const unsigned short* bk1 =
        (const unsigned short*)(ws + WS_AKL) + ((size_t)ct * 8 * 64 + lane) * 8;
#pragma unroll
    for (int i = 0; i < 16; ++i) { q1[i] = 0.f; q2[i] = 0.f; k1[i] = 0.f; k2[i] = 0.f; }
    s16x8 F[2][4];
    F[0][0] = *(const s16x8*)(bq0);
    F[0][1] = *(const s16x8*)(bq1);
    F[0][2] = *(const s16x8*)(bk0);
    F[0][3] = *(const s16x8*)(bk1);
#pragma unroll
    for (int q = 0; q < 8; ++q) {
      if (q < 7) {
        F[(q + 1) & 1][0] = *(const s16x8*)(bq0 + (q + 1) * 512);
        F[(q + 1) & 1][1] = *(const s16x8*)(bq1 + (q + 1) * 512);
        F[(q + 1) & 1][2] = *(const s16x8*)(bk0 + (q + 1) * 512);
        F[(q + 1) & 1][3] = *(const s16x8*)(bk1 + (q + 1) * 512);
      }
      __builtin_amdgcn_sched_barrier(0);       // loads stay issued HERE
      const s16x8 bh = *(const s16x8*)&U.HI[1][q][x0 + am + 1][kh][0];
      const s16x8 bl = *(const s16x8*)&BL[q][x0 + am + 1][kh][0];
      q1 = __builtin_amdgcn_mfma_f32_32x32x16_bf16(F[q & 1][0], bh, q1, 0, 0, 0);
      q1 = __builtin_amdgcn_mfma_f32_32x32x16_bf16(F[q & 1][1], bh, q1, 0, 0, 0);
      q2 = __builtin_amdgcn_mfma_f32_32x32x16_bf16(F[q & 1][0], bl, q2, 0, 0, 0);
      k1 = __builtin_amdgcn_mfma_f32_32x32x16_bf16(F[q & 1][2], bh, k1, 0, 0, 0);
      k1 = __builtin_amdgcn_mfma_f32_32x32x16_bf16(F[q & 1][3], bh, k1, 0, 0, 0);
      k2 = __builtin_amdgcn_mfma_f32_32x32x16_bf16(F[q & 1][2], bl, k2, 0, 0, 0);
      __builtin_amdgcn_sched_barrier(0);
    }
  }
  __syncthreads();                             // B2: HI/BL dead, overlay free

  // ---- spill accumulators to LDS overlay (stride 66) ----
  if (wave < 4) {
#pragma unroll
    for (int r = 0; r < 16; ++r) {
      const int c = ch0 + (r & 3) + 8 * (r >> 2) + 4 * kh;
      U.p.VAL[c * 66 + x0 + am] = acc[r] + Vb[c];
    }
  } else {
#pragma unroll
    for (int r = 0; r < 16; ++r) {
      const int c = ch0 + (r & 3) + 8 * (r >> 2) + 4 * kh;
      const float qvv = q1[r] + q2[r] + ws[WS_BQ + c];
      const float kvv = k1[r] + k2[r] + bk[c];
      U.p.QT[c * 66 + x0 + am] = qvv;
      l3part = fmaf(qvv, kvv, l3part);
    }
    if (ct == 1) l3red[xh][lane] = l3part;     // waves 6,7
  }
  __syncthreads();                             // B3: QT/VAL/l3red ready

  // ---- l3 finish: waves 4,5 ----
  if (wave == 4 || wave == 5) {
    float s = l3part + l3red[xh][lane];
    s += __shfl_xor(s, 32, 64);
    if (kh == 0) U.p.L3[x0 + am] = s;
  }
  __syncthreads();                             // B4: phase-B inputs ready
                                               // (LAST barrier in the kernel)

  // =======================================================================
  // Phase B: barrier-free streaming. wave -> (row u, 32-px window xw).
  // lane = pl(lane&7: px-quad) + cq(lane>>3: c-group); 8 c in-thread.
  // =======================================================================
  const int u   = wave & 1;
  const int xw  = wave >> 1;                   // 0..3
  const int pl  = lane & 7;
  const int cq  = lane >> 3;
  const int px  = xw * 32 + pl * 4;
  const int hx  = xw * 16 + pl * 2;
  const int hrow = 2 * y + u;
  const int cs = FS * FS;
  const float* cb = ctx + (size_t)(b * NCTX * CH) * cs + (size_t)hrow * FS + px;
  float* ob = out + (size_t)(b * CH) * cs + (size_t)hrow * FS + px;

  float2 qv[8];
#pragma unroll
  for (int i = 0; i < 8; ++i)
    qv[i] = *(const float2*)&U.p.QT[(cq * 8 + i) * 66 + hx];

  // logits: in-thread over 8 c, per n
  float4 pL[3];
#pragma unroll
  for (int n = 0; n < 3; ++n) {
    float4 cv[8];
#pragma unroll
    for (int i = 0; i < 8; ++i)
      cv[i] = *(const float4*)(cb + (size_t)(n * CH + cq * 8 + i) * cs);
    float4 s;
    s.x = s.y = s.z = s.w = 0.f;
#pragma unroll
    for (int i = 0; i < 8; ++i) {
      s.x = fmaf(cv[i].x, qv[i].x, s.x);
      s.y = fmaf(cv[i].y, qv[i].x, s.y);
      s.z = fmaf(cv[i].z, qv[i].y, s.z);
      s.w = fmaf(cv[i].w, qv[i].y, s.w);
    }
    pL[n] = s;
  }
  // in-wave reduce over the 8 cq groups (lane bits 3,4,5)
#pragma unroll
  for (int mk = 8; mk <= 32; mk <<= 1) {
#pragma unroll
    for (int n = 0; n < 3; ++n) {
      pL[n].x += __shfl_xor(pL[n].x, mk, 64);
      pL[n].y += __shfl_xor(pL[n].y, mk, 64);
      pL[n].z += __shfl_xor(pL[n].z, mk, 64);
      pL[n].w += __shfl_xor(pL[n].w, mk, 64);
    }
  }
  const float l3a = U.p.L3[hx], l3b = U.p.L3[hx + 1];

  float A0[4], A1[4], A2[4], A3[4];
  const float* L0p = (const float*)&pL[0];
  const float* L1p = (const float*)&pL[1];
  const float* L2p = (const float*)&pL[2];
#pragma unroll
  for (int k = 0; k < 4; ++k) {
    float L0 = L0p[k], L1 = L1p[k], L2 = L2p[k];
    float L3v = (k < 2) ? l3a : l3b;
    float mx = fmaxf(fmaxf(L0, L1), fmaxf(L2, L3v));
    float e0 = __expf(L0 - mx), e1 = __expf(L1 - mx);
    float e2 = __expf(L2 - mx), e3 = __expf(L3v - mx);
    float inv = 1.f / (e0 + e1 + e2 + e3);
    A0[k] = e0 * inv; A1[k] = e1 * inv; A2[k] = e2 * inv; A3[k] = e3 * inv;
  }

  // output: re-read ctx (hot L2) so cv needn't stay resident
#pragma unroll
  for (int i = 0; i < 8; ++i) {
    const int c = cq * 8 + i;
    const float2 vv = *(const float2*)&U.p.VAL[c * 66 + hx];
    const float4 c0v = *(const float4*)(cb + (size_t)(0 * CH + c) * cs);
    const float4 c1v = *(const float4*)(cb + (size_t)(1 * CH + c) * cs);
    const float4 c2v = *(const float4*)(cb + (size_t)(2 * CH + c) * cs);
    float4 o;
    o.x = fmaf(A0[0], c0v.x, fmaf(A1[0], c1v.x, fmaf(A2[0], c2v.x, A3[0] * vv.x)));
    o.y = fmaf(A0[1], c0v.y, fmaf(A1[1], c1v.y, fmaf(A2[1], c2v.y, A3[1] * vv.x)));
    o.z = fmaf(A0[2], c0v.z, fmaf(A1[2], c1v.z, fmaf(A2[2], c2v.z, A3[2] * vv.y)));
    o.w = fmaf(A0[3], c0v.w, fmaf(A1[3], c1v.w, fmaf(A2[3], c2v.w, A3[3] * vv.y)));
    *(float4*)(ob + (size_t)c * cs) = o;
  }
}

// ---------------------------------------------------------------------------
extern "C" void kernel_launch(void* const* d_in, const int* in_sizes, int n_in,
                              void* d_out, int out_size, void* d_ws, size_t ws_size,
                              hipStream_t stream) {
  const float* ctx = (const float*)d_in[0];
  const float* ms  = (const float*)d_in[1];
  const float* Wc  = (const float*)d_in[2];
  // d_in[3] = bc : cancels in softmax
  const float* Wf  = (const float*)d_in[4];
  const float* bf  = (const float*)d_in[5];
  const float* Wk  = (const float*)d_in[6];
  const float* bk  = (const float*)d_in[7];
  const float* Vw  = (const float*)d_in[8];
  const float* Vb  = (const float*)d_in[9];
  float* ws  = (float*)d_ws;
  float* out = (float*)d_out;

  afrag_prep<<<45, 256, 0, stream>>>(Wc, Wf, bf, Wk, Vw, ws);
  fused_kernel<<<NB * HS, 512, 0, stream>>>(ms, Vb, bk, ctx, out, ws);
}